// Round 19
// baseline (31.307 us; speedup 1.0000x reference)
//
#include <hip/hip_runtime.h>
#include <hip/hip_fp16.h>

#define D 300
#define NS 256
#define NA 256
#define W 8
#define NPH 5        // 5 K-phases x 64 elements (K padded 300 -> 320)

typedef _Float16 half8 __attribute__((ext_vector_type(8)));
typedef float f32x4 __attribute__((ext_vector_type(4)));

// Single dispatch, 256 blocks x 512 threads.
// Waves 0-3: MFMA consumers (128x128 tile). Waves 4-7: staging producers + out2.
// LDS 64 KB: stage[2][A 16KB | B 16KB]; overlays: buf1 -> rsc[256], buf0 -> fp16 cos.
__global__ __launch_bounds__(512, 1) void k_all(const float* __restrict__ emb,
                                                const int* __restrict__ sen_cats,
                                                const int* __restrict__ ann_cats,
                                                const int* __restrict__ none_idx,
                                                float* __restrict__ out) {
    __shared__ float smem[16384];   // 64 KB
    _Float16* stage = reinterpret_cast<_Float16*>(smem);
    float* rsc = smem + 8192;                             // overlays buf1
    _Float16* cosld = reinterpret_cast<_Float16*>(smem);  // overlays buf0

    int tid = threadIdx.x;
    int blk = blockIdx.x;
    int by = blk >> 4, bx = blk & 15;
    int wv = tid >> 6, lane = tid & 63;
    bool producer = (wv >= 4);

    if (producer) {
        // ================= PRODUCER waves (tid 256..511) =================
        int ptid = tid - 256;
        int g = ptid >> 4, f0 = ptid & 15;     // row-in-16, k-phase float4
        int c0 = f0 >> 3, lk0 = (f0 & 7) >> 1, e0 = (f0 & 1) * 4;
        const float* rowp[16];
        int catA[8];
#pragma unroll
        for (int j = 0; j < 8; ++j) {          // A rows (sen)
            catA[j] = sen_cats[by * 128 + g + j * 16];
            rowp[j] = emb + (size_t)catA[j] * D;
        }
#pragma unroll
        for (int j = 8; j < 16; ++j) {         // B rows (ann)
            int cb = ann_cats[bx * 128 + g + (j - 8) * 16];
            rowp[j] = emb + (size_t)cb * D;
        }

        float4 pf[16];
        float na[16];
#pragma unroll
        for (int j = 0; j < 16; ++j) na[j] = 0.f;

#define PH_LOAD(p)                                                            \
    {                                                                         \
        int gk = (p) * 64 + f0 * 4;                                           \
        bool ok = ((p) < 4) || (f0 <= 10);                                    \
        _Pragma("unroll")                                                     \
        for (int j = 0; j < 16; ++j)                                          \
            pf[j] = ok ? *reinterpret_cast<const float4*>(rowp[j] + gk)       \
                       : make_float4(0.f, 0.f, 0.f, 0.f);                     \
    }
#define PH_WRITE(b)                                                           \
    {                                                                         \
        _Pragma("unroll")                                                     \
        for (int j = 0; j < 16; ++j) {                                        \
            float4 v = pf[j];                                                 \
            na[j] = fmaf(v.x, v.x, na[j]); na[j] = fmaf(v.y, v.y, na[j]);     \
            na[j] = fmaf(v.z, v.z, na[j]); na[j] = fmaf(v.w, v.w, na[j]);     \
            ushort4 h;                                                        \
            h.x = __half_as_ushort(__float2half(v.x));                        \
            h.y = __half_as_ushort(__float2half(v.y));                        \
            h.z = __half_as_ushort(__float2half(v.z));                        \
            h.w = __half_as_ushort(__float2half(v.w));                        \
            int rt = (j < 8) ? j : (j - 8);                                   \
            int off = (b) * 16384 + ((j < 8) ? 0 : 8192) +                    \
                      ((rt * 2 + c0) * 64 + lk0 * 16 + g) * 8 + e0;           \
            *reinterpret_cast<ushort4*>(stage + off) = h;                     \
        }                                                                     \
    }

        PH_LOAD(0);
        PH_WRITE(0);
        __syncthreads();                       // buf0 ready

#pragma unroll
        for (int p = 0; p < NPH; ++p) {
            if (p + 1 < NPH) {
                PH_LOAD(p + 1);
                PH_WRITE((p + 1) & 1);
            } else {
                // last phase: consumers read buf0; buf1 is free -> write rsc
                int nidx = none_idx[0];
#pragma unroll
                for (int j = 0; j < 16; ++j) {
                    float s = na[j];
                    s += __shfl_xor(s, 1, 64);
                    s += __shfl_xor(s, 2, 64);
                    s += __shfl_xor(s, 4, 64);
                    s += __shfl_xor(s, 8, 64);
                    if (f0 == 0) {
                        float rn = (float)(1.0 / sqrt((double)s));
                        if (j < 8 && catA[j] == nidx) rn = 0.f;
                        rsc[g + ((j < 8) ? j * 16 : 128 + (j - 8) * 16)] = rn;
                    }
                }
            }
            __syncthreads();                   // phase boundary
        }

        // out2: category blk (75 float4 positions over threads), w-ascending
        if (ptid < 75) {
            float4 s = make_float4(0.f, 0.f, 0.f, 0.f);
#pragma unroll
            for (int w = 0; w < W; ++w) {
                int cat = sen_cats[blk * W + w];
                float4 v = reinterpret_cast<const float4*>(emb + (size_t)cat * D)[ptid];
                s.x += v.x; s.y += v.y; s.z += v.z; s.w += v.w;
            }
            reinterpret_cast<float4*>(out + NS * NA + (size_t)blk * D)[ptid] = s;
        }
        __syncthreads();                       // epilogue cos written (consumers)
        // producers done (fold handled by consumer half)
#undef PH_LOAD
#undef PH_WRITE
    } else {
        // ================= CONSUMER waves (tid 0..255) =================
        int wy = wv >> 1, wx = wv & 1;
        int lr = lane & 15, lk = lane >> 4;

        f32x4 acc[4][4] = {};
        __syncthreads();                       // buf0 ready

#pragma unroll
        for (int p = 0; p < NPH; ++p) {
            int bb = (p & 1) * 16384;
#pragma unroll
            for (int c = 0; c < 2; ++c) {      // global chunk 2p+c (ascending)
                half8 Ah[4], Bh[4];
#pragma unroll
                for (int m = 0; m < 4; ++m)
                    Ah[m] = *reinterpret_cast<const half8*>(
                        stage + bb + (((wy * 4 + m) * 2 + c) * 64 + lane) * 8);
#pragma unroll
                for (int n = 0; n < 4; ++n)
                    Bh[n] = *reinterpret_cast<const half8*>(
                        stage + bb + 8192 + (((wx * 4 + n) * 2 + c) * 64 + lane) * 8);
#pragma unroll
                for (int m = 0; m < 4; ++m)
#pragma unroll
                    for (int n = 0; n < 4; ++n)
                        acc[m][n] = __builtin_amdgcn_mfma_f32_16x16x32_f16(
                            Ah[m], Bh[n], acc[m][n], 0, 0, 0);
            }
            __syncthreads();                   // phase boundary
        }

        // epilogue: cos -> fp16 tile in buf0 (C/D: col=lane&15, row=lk*4+reg)
#pragma unroll
        for (int m = 0; m < 4; ++m) {
            int rbase = wy * 64 + m * 16 + lk * 4;
#pragma unroll
            for (int r = 0; r < 4; ++r) {
                float sA = rsc[rbase + r];
#pragma unroll
                for (int n = 0; n < 4; ++n) {
                    int lc = wx * 64 + n * 16 + lr;
                    float sB = rsc[128 + lc];
                    cosld[(rbase + r) * 128 + lc] = (_Float16)(acc[m][n][r] * sA * sB);
                }
            }
        }
        __syncthreads();                       // cos tile complete

        // fold: one (s,a) pair per consumer thread, w-major order
        int pi = tid >> 4, pj = tid & 15;
        float cur = 0.f;
#pragma unroll
        for (int w = 0; w < W; ++w) {
            const _Float16* rp = &cosld[(pi * 8 + w) * 128 + pj * 8];
#pragma unroll
            for (int v = 0; v < W; ++v) {
                float sv = (float)rp[v];
                cur = (sv >= cur || sv < 0.f) ? sv : cur;
            }
        }
        out[(by * 16 + pi) * NA + (bx * 16 + pj)] = cur;
    }
}

extern "C" void kernel_launch(void* const* d_in, const int* in_sizes, int n_in,
                              void* d_out, int out_size, void* d_ws, size_t ws_size,
                              hipStream_t stream) {
    const float* emb = (const float*)d_in[0];
    const int* sen = (const int*)d_in[1];
    const int* ann = (const int*)d_in[2];
    const int* none = (const int*)d_in[3];
    float* out = (float*)d_out;

    hipLaunchKernelGGL(k_all, dim3(256), dim3(512), 0, stream,
                       emb, sen, ann, none, out);
}

// Round 20
// 21.626 us; speedup vs baseline: 1.4476x; 1.4476x over previous
//
#include <hip/hip_runtime.h>
#include <hip/hip_fp16.h>

#define D 300
#define NS 256
#define NA 256
#define W 8
#define NCHUNK 10     // K padded to 10 chunks of 32 (320)

typedef _Float16 half8 __attribute__((ext_vector_type(8)));
typedef float f32x4 __attribute__((ext_vector_type(4)));

__device__ __forceinline__ ushort4 cvt4(float4 v) {
    ushort4 h;
    h.x = __half_as_ushort(__float2half(v.x));
    h.y = __half_as_ushort(__float2half(v.y));
    h.z = __half_as_ushort(__float2half(v.z));
    h.w = __half_as_ushort(__float2half(v.w));
    return h;
}

// ---- prep: 256 blocks (1/CU), 16 rows/block, LDS tile + coalesced slab dump ----
__global__ __launch_bounds__(256) void k_prep(const float* __restrict__ emb,
                                              const int* __restrict__ sen_cats,
                                              const int* __restrict__ ann_cats,
                                              const int* __restrict__ none_idx,
                                              unsigned short* __restrict__ AH,
                                              unsigned short* __restrict__ BH,
                                              float* __restrict__ rsn,
                                              float* __restrict__ ran,
                                              int* __restrict__ sflag) {
    // swizzled tile for one rt: [c(10)][lane(64)][e(8)] halves = 10,240 B
    __shared__ _Float16 tile[NCHUNK][64][8];

    int blk = blockIdx.x, t = threadIdx.x;
    bool isSen = blk < 128;
    int rt = isSen ? blk : blk - 128;
    const int* cats = isSen ? sen_cats : ann_cats;
    unsigned short* HI = isSen ? AH : BH;

    int lr = t >> 4, f0 = t & 15;          // row-in-tile, float4 phase
    int r = rt * 16 + lr;
    int cat = cats[r];
    const float4* src = reinterpret_cast<const float4*>(emb + (size_t)cat * D);

    double acc = 0.0;
#pragma unroll
    for (int j = 0; j < 5; ++j) {
        int fidx = f0 + 16 * j;            // 0..79
        int k0 = fidx * 4;
        int c = k0 >> 5, lk = (k0 & 31) >> 3, e = k0 & 7;   // e in {0,4}
        ushort4* dp = reinterpret_cast<ushort4*>(&tile[c][lk * 16 + lr][e]);
        if (fidx < 75) {
            float4 v = src[fidx];
            *dp = cvt4(v);
            acc += (double)v.x * v.x + (double)v.y * v.y +
                   (double)v.z * v.z + (double)v.w * v.w;
        } else {                           // fidx 75..79 -> zero K-pad
            ushort4 z = {0, 0, 0, 0};
            *dp = z;
        }
    }
    // norm reduce within each 16-lane row group
    for (int m = 8; m > 0; m >>= 1) acc += __shfl_xor(acc, m, 64);
    if (f0 == 0) {
        float rn = (float)(1.0 / sqrt(acc));   // norms ~17, eps unreachable
        if (isSen) {
            rsn[r] = rn;
            sflag[r] = (cat == none_idx[0]) ? 1 : 0;
        } else {
            ran[r] = rn;
        }
    }
    __syncthreads();
    // coalesced slab dump: 640 float4 = 10,240 B contiguous
    const float4* tl = reinterpret_cast<const float4*>(&tile[0][0][0]);
    float4* dst = reinterpret_cast<float4*>(HI + (size_t)rt * 5120);
    dst[t] = tl[t];
    dst[t + 256] = tl[t + 256];
    if (t < 128) dst[t + 512] = tl[t + 512];
}

// ---- main: single-pass fp16 MFMA (r11/r16 body) + out2 tail on wave 0 ----
__global__ __launch_bounds__(256, 1) void k_main(const float* __restrict__ emb,
                                                 const int* __restrict__ sen_cats,
                                                 const unsigned short* __restrict__ AHu,
                                                 const unsigned short* __restrict__ BHu,
                                                 const float* __restrict__ rsn,
                                                 const float* __restrict__ ran,
                                                 const int* __restrict__ sflag,
                                                 float* __restrict__ out) {
    const _Float16* AH = reinterpret_cast<const _Float16*>(AHu);
    const _Float16* BH = reinterpret_cast<const _Float16*>(BHu);

    __shared__ float cosld[128][128];   // 64 KB exactly

    int tid = threadIdx.x;
    int wv = tid >> 6, lane = tid & 63;
    int wy = wv >> 1, wx = wv & 1;      // wave's 64x64 quadrant
    int lr = lane & 15;
    int lk = lane >> 4;
    int by = blockIdx.y, bx = blockIdx.x;

    int aBase[4], bBase[4];
#pragma unroll
    for (int m = 0; m < 4; ++m)
        aBase[m] = (((by * 8 + wy * 4 + m) * NCHUNK) * 64 + lane) * 8;
#pragma unroll
    for (int n = 0; n < 4; ++n)
        bBase[n] = (((bx * 8 + wx * 4 + n) * NCHUNK) * 64 + lane) * 8;

    f32x4 acc[4][4] = {};
    half8 Ah[4], Bh[4];

#pragma unroll
    for (int c = 0; c < NCHUNK; ++c) {
        int co = c * 512;
#pragma unroll
        for (int m = 0; m < 4; ++m)
            Ah[m] = *reinterpret_cast<const half8*>(AH + aBase[m] + co);
#pragma unroll
        for (int n = 0; n < 4; ++n)
            Bh[n] = *reinterpret_cast<const half8*>(BH + bBase[n] + co);
#pragma unroll
        for (int m = 0; m < 4; ++m)
#pragma unroll
            for (int n = 0; n < 4; ++n)
                acc[m][n] = __builtin_amdgcn_mfma_f32_16x16x32_f16(Ah[m], Bh[n], acc[m][n], 0, 0, 0);
    }

    // epilogue: cosine scale (C/D: col=lane&15, row=(lane>>4)*4+reg) -> LDS
#pragma unroll
    for (int m = 0; m < 4; ++m) {
        int rbase = wy * 64 + m * 16 + lk * 4;
#pragma unroll
        for (int r = 0; r < 4; ++r) {
            int grow = by * 128 + rbase + r;
            float rsv = rsn[grow];
            float fm = sflag[grow] ? 0.f : 1.f;
            float rf = rsv * fm;
#pragma unroll
            for (int n = 0; n < 4; ++n) {
                int lc = wx * 64 + n * 16 + lr;
                float rav = ran[bx * 128 + lc];
                cosld[rbase + r][lc] = acc[m][n][r] * rf * rav;
            }
        }
    }
    __syncthreads();

    // order-dependent fold: one (s,a) pair per thread, w-major order
    int pi = tid >> 4, pj = tid & 15;
    float cur = 0.f;
#pragma unroll
    for (int w = 0; w < W; ++w) {
        const float* rowp = &cosld[pi * 8 + w][pj * 8];
#pragma unroll
        for (int v = 0; v < W; ++v) {
            float sv = rowp[v];
            cur = (sv >= cur || sv < 0.f) ? sv : cur;
        }
    }
    out[(by * 16 + pi) * NA + (bx * 16 + pj)] = cur;

    // out2 tail: wave 0 computes sen category blk (rows L2/L3-warm from prep)
    if (wv == 0) {
        int cb = by * 16 + bx;
        float4 s0 = make_float4(0.f, 0.f, 0.f, 0.f);
        float4 s1 = make_float4(0.f, 0.f, 0.f, 0.f);
#pragma unroll
        for (int w = 0; w < W; ++w) {          // w-ascending fp32 adds (ref order)
            int cat = sen_cats[cb * W + w];
            const float4* src = reinterpret_cast<const float4*>(emb + (size_t)cat * D);
            float4 v0 = src[lane];
            s0.x += v0.x; s0.y += v0.y; s0.z += v0.z; s0.w += v0.w;
            if (lane < 11) {
                float4 v1 = src[lane + 64];
                s1.x += v1.x; s1.y += v1.y; s1.z += v1.z; s1.w += v1.w;
            }
        }
        float4* o = reinterpret_cast<float4*>(out + NS * NA + (size_t)cb * D);
        o[lane] = s0;
        if (lane < 11) o[lane + 64] = s1;
    }
}

extern "C" void kernel_launch(void* const* d_in, const int* in_sizes, int n_in,
                              void* d_out, int out_size, void* d_ws, size_t ws_size,
                              hipStream_t stream) {
    const float* emb = (const float*)d_in[0];
    const int* sen = (const int*)d_in[1];
    const int* ann = (const int*)d_in[2];
    const int* none = (const int*)d_in[3];
    float* out = (float*)d_out;

    char* ws = (char*)d_ws;
    unsigned short* AH = (unsigned short*)(ws + 0);          // 2048*320*2 = 1,310,720
    unsigned short* BH = (unsigned short*)(ws + 1310720);    // 1,310,720
    float* rsn = (float*)(ws + 2621440);                     // 8,192
    float* ran = (float*)(ws + 2629632);                     // 8,192
    int* sflag = (int*)(ws + 2637824);                       // 8,192

    hipLaunchKernelGGL(k_prep, dim3(256), dim3(256), 0, stream,
                       emb, sen, ann, none, AH, BH, rsn, ran, sflag);
    hipLaunchKernelGGL(k_main, dim3(16, 16), dim3(256), 0, stream,
                       emb, sen, AH, BH, rsn, ran, sflag, out);
}

// Round 21
// 19.619 us; speedup vs baseline: 1.5958x; 1.1023x over previous
//
#include <hip/hip_runtime.h>
#include <hip/hip_fp16.h>

#define D 300
#define NS 256
#define NA 256
#define W 8
#define NROWS 2048    // 256*8
#define NCHUNK 10     // K padded to 10 chunks of 32 (320)

typedef _Float16 half8 __attribute__((ext_vector_type(8)));
typedef float f32x4 __attribute__((ext_vector_type(4)));

__device__ __forceinline__ ushort4 cvt4(float4 v) {
    ushort4 h;
    h.x = __half_as_ushort(__float2half(v.x));
    h.y = __half_as_ushort(__float2half(v.y));
    h.z = __half_as_ushort(__float2half(v.z));
    h.w = __half_as_ushort(__float2half(v.w));
    return h;
}

// ---- prep: blocks 0..255 = slab gather (16 rows/block, coalesced slab dump);
//            blocks 256..319 = out2 (one wave per sen category) ----
__global__ __launch_bounds__(256) void k_prep(const float* __restrict__ emb,
                                              const int* __restrict__ sen_cats,
                                              const int* __restrict__ ann_cats,
                                              const int* __restrict__ none_idx,
                                              unsigned short* __restrict__ AH,
                                              unsigned short* __restrict__ BH,
                                              float* __restrict__ rsn,
                                              float* __restrict__ ran,
                                              int* __restrict__ sflag,
                                              float* __restrict__ out2) {
    // swizzled tile for one rt: [c(10)][lane(64)][e(8)] halves = 10,240 B
    __shared__ _Float16 tile[NCHUNK][64][8];

    int blk = blockIdx.x, t = threadIdx.x;
    if (blk < 256) {
        bool isSen = blk < 128;
        int rt = isSen ? blk : blk - 128;
        const int* cats = isSen ? sen_cats : ann_cats;
        unsigned short* HI = isSen ? AH : BH;

        int lr = t >> 4, f0 = t & 15;          // row-in-tile, float4 phase
        int r = rt * 16 + lr;
        int cat = cats[r];
        const float4* src = reinterpret_cast<const float4*>(emb + (size_t)cat * D);

        double acc = 0.0;
#pragma unroll
        for (int j = 0; j < 5; ++j) {
            int fidx = f0 + 16 * j;            // 0..79
            int k0 = fidx * 4;
            int c = k0 >> 5, lk = (k0 & 31) >> 3, e = k0 & 7;   // e in {0,4}
            ushort4* dp = reinterpret_cast<ushort4*>(&tile[c][lk * 16 + lr][e]);
            if (fidx < 75) {
                float4 v = src[fidx];
                *dp = cvt4(v);
                acc += (double)v.x * v.x + (double)v.y * v.y +
                       (double)v.z * v.z + (double)v.w * v.w;
            } else {                           // fidx 75..79 -> zero K-pad
                ushort4 z = {0, 0, 0, 0};
                *dp = z;
            }
        }
        // norm reduce within each 16-lane row group
        for (int m = 8; m > 0; m >>= 1) acc += __shfl_xor(acc, m, 64);
        if (f0 == 0) {
            float rn = (float)(1.0 / sqrt(acc));   // norms ~17, eps unreachable
            if (isSen) {
                rsn[r] = rn;
                sflag[r] = (cat == none_idx[0]) ? 1 : 0;
            } else {
                ran[r] = rn;
            }
        }
        __syncthreads();
        // coalesced slab dump: 640 float4 = 10,240 B contiguous
        const float4* tl = reinterpret_cast<const float4*>(&tile[0][0][0]);
        float4* dst = reinterpret_cast<float4*>(HI + (size_t)rt * 5120);
        dst[t] = tl[t];
        dst[t + 256] = tl[t + 256];
        if (t < 128) dst[t + 512] = tl[t + 512];
    } else {
        // ----- out2: one wave per sen category (w-ascending fp32 adds) -----
        int wv = t >> 6, lane = t & 63;
        int cb = (blk - 256) * 4 + wv;
        float4 s0 = make_float4(0.f, 0.f, 0.f, 0.f);
        float4 s1 = make_float4(0.f, 0.f, 0.f, 0.f);
#pragma unroll
        for (int w = 0; w < W; ++w) {
            int cat = sen_cats[cb * W + w];
            const float4* src = reinterpret_cast<const float4*>(emb + (size_t)cat * D);
            float4 v0 = src[lane];
            s0.x += v0.x; s0.y += v0.y; s0.z += v0.z; s0.w += v0.w;
            if (lane < 11) {
                float4 v1 = src[lane + 64];
                s1.x += v1.x; s1.y += v1.y; s1.z += v1.z; s1.w += v1.w;
            }
        }
        float4* o = reinterpret_cast<float4*>(out2 + (size_t)cb * D);
        o[lane] = s0;
        if (lane < 11) o[lane + 64] = s1;
    }
}

// ---- main: single-pass fp16 MFMA, XCD-aware tile swizzle (T1) ----
__global__ __launch_bounds__(256, 1) void k_main(const unsigned short* __restrict__ AHu,
                                                 const unsigned short* __restrict__ BHu,
                                                 const float* __restrict__ rsn,
                                                 const float* __restrict__ ran,
                                                 const int* __restrict__ sflag,
                                                 float* __restrict__ out) {
    const _Float16* AH = reinterpret_cast<const _Float16*>(AHu);
    const _Float16* BH = reinterpret_cast<const _Float16*>(BHu);

    __shared__ float cosld[128][128];   // 64 KB exactly

    int tid = threadIdx.x;
    int wv = tid >> 6, lane = tid & 63;
    int wy = wv >> 1, wx = wv & 1;      // wave's 64x64 quadrant
    int lr = lane & 15;
    int lk = lane >> 4;

    // T1: HW maps wg i -> XCD (i % 8). Give each XCD a contiguous 4x8 tile
    // rectangle so its L2 holds 4 A-panels + 8 B-panels (960 KB << 4 MB).
    int blk = blockIdx.x;
    int xcd = blk & 7, j = blk >> 3;
    int by = (xcd >> 1) * 4 + (j >> 3);
    int bx = (xcd & 1) * 8 + (j & 7);

    int aBase[4], bBase[4];
#pragma unroll
    for (int m = 0; m < 4; ++m)
        aBase[m] = (((by * 8 + wy * 4 + m) * NCHUNK) * 64 + lane) * 8;
#pragma unroll
    for (int n = 0; n < 4; ++n)
        bBase[n] = (((bx * 8 + wx * 4 + n) * NCHUNK) * 64 + lane) * 8;

    f32x4 acc[4][4] = {};
    half8 Ah[4], Bh[4];

#pragma unroll
    for (int c = 0; c < NCHUNK; ++c) {
        int co = c * 512;
#pragma unroll
        for (int m = 0; m < 4; ++m)
            Ah[m] = *reinterpret_cast<const half8*>(AH + aBase[m] + co);
#pragma unroll
        for (int n = 0; n < 4; ++n)
            Bh[n] = *reinterpret_cast<const half8*>(BH + bBase[n] + co);
#pragma unroll
        for (int m = 0; m < 4; ++m)
#pragma unroll
            for (int n = 0; n < 4; ++n)
                acc[m][n] = __builtin_amdgcn_mfma_f32_16x16x32_f16(Ah[m], Bh[n], acc[m][n], 0, 0, 0);
    }

    // epilogue: cosine scale (C/D: col=lane&15, row=(lane>>4)*4+reg) -> LDS
#pragma unroll
    for (int m = 0; m < 4; ++m) {
        int rbase = wy * 64 + m * 16 + lk * 4;
#pragma unroll
        for (int r = 0; r < 4; ++r) {
            int grow = by * 128 + rbase + r;
            float rsv = rsn[grow];
            float fm = sflag[grow] ? 0.f : 1.f;
            float rf = rsv * fm;
#pragma unroll
            for (int n = 0; n < 4; ++n) {
                int lc = wx * 64 + n * 16 + lr;
                float rav = ran[bx * 128 + lc];
                cosld[rbase + r][lc] = acc[m][n][r] * rf * rav;
            }
        }
    }
    __syncthreads();

    // order-dependent fold: one (s,a) pair per thread, w-major order
    int pi = tid >> 4, pj = tid & 15;
    float cur = 0.f;
#pragma unroll
    for (int w = 0; w < W; ++w) {
        const float* rowp = &cosld[pi * 8 + w][pj * 8];
#pragma unroll
        for (int v = 0; v < W; ++v) {
            float sv = rowp[v];
            cur = (sv >= cur || sv < 0.f) ? sv : cur;
        }
    }
    out[(by * 16 + pi) * NA + (bx * 16 + pj)] = cur;
}

extern "C" void kernel_launch(void* const* d_in, const int* in_sizes, int n_in,
                              void* d_out, int out_size, void* d_ws, size_t ws_size,
                              hipStream_t stream) {
    const float* emb = (const float*)d_in[0];
    const int* sen = (const int*)d_in[1];
    const int* ann = (const int*)d_in[2];
    const int* none = (const int*)d_in[3];
    float* out = (float*)d_out;

    char* ws = (char*)d_ws;
    unsigned short* AH = (unsigned short*)(ws + 0);          // 2048*320*2 = 1,310,720
    unsigned short* BH = (unsigned short*)(ws + 1310720);    // 1,310,720
    float* rsn = (float*)(ws + 2621440);                     // 8,192
    float* ran = (float*)(ws + 2629632);                     // 8,192
    int* sflag = (int*)(ws + 2637824);                       // 8,192

    hipLaunchKernelGGL(k_prep, dim3(320), dim3(256), 0, stream,
                       emb, sen, ann, none, AH, BH, rsn, ran, sflag,
                       out + NS * NA);
    hipLaunchKernelGGL(k_main, dim3(256), dim3(256), 0, stream,
                       AH, BH, rsn, ran, sflag, out);
}